// Round 5
// baseline (389.373 us; speedup 1.0000x reference)
//
#include <hip/hip_runtime.h>
#include <math.h>

#define WAY 5
#define SHOT 5
#define HEADS 12
#define DIM 768
#define LSEQ 512
#define HD 64
#define NROWS (WAY*SHOT*LSEQ)   // 12800
#define SCALE 0.125f
#define NXEL ((size_t)NROWS*DIM)
#define NWEL ((size_t)DIM*DIM)

typedef __attribute__((ext_vector_type(8))) short short8;
typedef __attribute__((ext_vector_type(4))) float f32x4;
typedef __attribute__((ext_vector_type(4))) unsigned short ushort4v;

__device__ __forceinline__ float bf2f(unsigned short u) {
    union { unsigned int i; float f; } x; x.i = ((unsigned int)u) << 16; return x.f;
}
__device__ __forceinline__ unsigned short f2bf(float f) {
    union { float f; unsigned int i; } x; x.f = f;
    unsigned int r = x.i + 0x7FFFu + ((x.i >> 16) & 1u);
    return (unsigned short)(r >> 16);
}

// ---------------------------------------------------------------------------
// K0: all fp32->bf16 casts in one launch.
// ---------------------------------------------------------------------------
#define NX4 (NROWS*DIM/4)
#define NW4 (DIM*DIM/4)
__global__ __launch_bounds__(256) void cast_all(
    const float* __restrict__ X, const float* __restrict__ Wq,
    const float* __restrict__ Wk, const float* __restrict__ Wv,
    unsigned short* __restrict__ Xb, unsigned short* __restrict__ Wb)
{
    int i = blockIdx.x * 256 + threadIdx.x;
    const float* s; unsigned short* d; int off;
    if (i < NX4)               { s = X;  d = Xb;            off = i; }
    else if (i < NX4 + NW4)    { s = Wq; d = Wb;            off = i - NX4; }
    else if (i < NX4 + 2*NW4)  { s = Wk; d = Wb + NWEL;     off = i - NX4 - NW4; }
    else if (i < NX4 + 3*NW4)  { s = Wv; d = Wb + 2*NWEL;   off = i - NX4 - 2*NW4; }
    else return;
    float4 f = ((const float4*)s)[off];
    ushort4v o;
    o.x = f2bf(f.x); o.y = f2bf(f.y); o.z = f2bf(f.z); o.w = f2bf(f.w);
    *(ushort4v*)(d + (size_t)off*4) = o;
}

// ---------------------------------------------------------------------------
// K1: fused QKV projection, bf16 MFMA 16x16x32, 128x128 tile, BK=32
// (R3 config: 16 KB LDS -> best occupancy), global_load_lds width-16.
// grid = (6, 100, 3), block = 256.
// ---------------------------------------------------------------------------
__global__ __launch_bounds__(256) void qkv_mfma(
    const unsigned short* __restrict__ Xb, const unsigned short* __restrict__ Wball,
    const float* __restrict__ bq, const float* __restrict__ bk, const float* __restrict__ bv,
    unsigned short* __restrict__ qkv_out)
{
    const int which = blockIdx.z;
    const unsigned short* W = Wball + (size_t)which * NWEL;
    const float* bias = (which == 0) ? bq : ((which == 1) ? bk : bv);
    unsigned short* out = qkv_out + (size_t)which * NXEL;

    const int m0 = blockIdx.y * 128;
    const int n0 = blockIdx.x * 128;

    __shared__ __align__(16) unsigned short Ab[128*32];
    __shared__ __align__(16) unsigned short Bb[128*32];

    const int t = threadIdx.x;
    const int w = t >> 6;
    const int lane = t & 63;
    const int quad = lane >> 4;
    const int l15 = lane & 15;
    const int wm = (w & 1) * 64;
    const int wn = (w >> 1) * 64;

    f32x4 acc[4][4];
    #pragma unroll
    for (int i = 0; i < 4; i++)
        #pragma unroll
        for (int j = 0; j < 4; j++)
            acc[i][j] = (f32x4){0.f, 0.f, 0.f, 0.f};

    const int srow = lane >> 2;
    const int schunk = (lane & 3) * 8;

    for (int k0 = 0; k0 < DIM; k0 += 32) {
        #pragma unroll
        for (int c = 0; c < 2; c++) {
            const unsigned short* gA = Xb + (size_t)(m0 + w*32 + c*16 + srow)*DIM + k0 + schunk;
            const unsigned short* gB = W  + (size_t)(n0 + w*32 + c*16 + srow)*DIM + k0 + schunk;
            __builtin_amdgcn_global_load_lds(
                (const __attribute__((address_space(1))) unsigned int*)gA,
                (__attribute__((address_space(3))) unsigned int*)&Ab[(w*32 + c*16)*32], 16, 0, 0);
            __builtin_amdgcn_global_load_lds(
                (const __attribute__((address_space(1))) unsigned int*)gB,
                (__attribute__((address_space(3))) unsigned int*)&Bb[(w*32 + c*16)*32], 16, 0, 0);
        }
        __syncthreads();

        short8 af[4], bf_[4];
        #pragma unroll
        for (int i = 0; i < 4; i++) af[i]  = *(const short8*)&Ab[(wm + i*16 + l15)*32 + quad*8];
        #pragma unroll
        for (int j = 0; j < 4; j++) bf_[j] = *(const short8*)&Bb[(wn + j*16 + l15)*32 + quad*8];
        #pragma unroll
        for (int i = 0; i < 4; i++)
            #pragma unroll
            for (int j = 0; j < 4; j++)
                acc[i][j] = __builtin_amdgcn_mfma_f32_16x16x32_bf16(af[i], bf_[j], acc[i][j], 0, 0, 0);
        __syncthreads();
    }

    #pragma unroll
    for (int j = 0; j < 4; j++) {
        const int col = n0 + wn + j*16 + l15;
        const float bv_ = bias[col];
        #pragma unroll
        for (int i = 0; i < 4; i++) {
            #pragma unroll
            for (int r = 0; r < 4; r++) {
                const int row = m0 + wm + i*16 + quad*4 + r;
                out[(size_t)row*DIM + col] = f2bf(acc[i][j][r] + bv_);
            }
        }
    }
}

// XOR-swizzled LDS addressing: 64-ushort (128 B) rows, 8 x 16B units per row.
__device__ __forceinline__ int swz(int row, int u) {
    return row*64 + ((u ^ (row & 7)) << 3);
}

// ---------------------------------------------------------------------------
// K2: branch-1 token attention.  grid = (300, 2), block = 256 (4 waves).
// Each block: 256 q-rows (wave w owns rows yc*256 + w*64 .. +63, Q-fragments
// in registers).  K and V-transposed staged once per key-tile per block (2x
// redundancy).  P staged per-m-tile in a 2 KB/wave buffer -> 25 KB LDS total
// -> 6 blocks/CU.  Unnormalized exp (scores tiny), one end reduction.
// Output: a1p[whs][yc][64] partial column-max; combine() max-reduces yc.
// ---------------------------------------------------------------------------
__global__ __launch_bounds__(256) void attn1_mfma(
    const unsigned short* __restrict__ qb, const unsigned short* __restrict__ kb,
    const unsigned short* __restrict__ vb, float* __restrict__ a1p)
{
    const int whs = blockIdx.x;
    const int yc  = blockIdx.y;
    const int si = whs % SHOT;
    const int hi = (whs / SHOT) % HEADS;
    const int wi = whs / (SHOT*HEADS);
    const size_t baseRow = (size_t)(wi*SHOT + si) * LSEQ;
    const int colBase = hi * HD;

    __shared__ __align__(16) unsigned short Ks[64*64];
    __shared__ __align__(16) unsigned short Vt[64*64];     // [d][l]
    __shared__ __align__(16) unsigned short Pb[4][16*64];  // per-wave, per-m
    __shared__ float cmaxs[4][64];

    const int t = threadIdx.x;
    const int w = t >> 6;
    const int lane = t & 63;
    const int quad = lane >> 4;
    const int l15 = lane & 15;

    // Q fragments in registers: rows yc*256 + w*64 + m*16 + l15
    short8 aq[4][2];
    #pragma unroll
    for (int m = 0; m < 4; m++)
        #pragma unroll
        for (int kk = 0; kk < 2; kk++)
            aq[m][kk] = *(const short8*)&qb[(baseRow + yc*256 + w*64 + m*16 + l15)*DIM
                                            + colBase + kk*32 + quad*8];

    float l_part[4][4];
    #pragma unroll
    for (int m = 0; m < 4; m++)
        #pragma unroll
        for (int r = 0; r < 4; r++) l_part[m][r] = 0.f;
    f32x4 o_acc[4][4];   // [m][dt]
    #pragma unroll
    for (int m = 0; m < 4; m++)
        #pragma unroll
        for (int dt = 0; dt < 4; dt++) o_acc[m][dt] = (f32x4){0.f,0.f,0.f,0.f};

    for (int kt = 0; kt < 8; kt++) {
        __syncthreads();
        // stage K row-major + V transposed (each thread: 2 tiles' worth)
        #pragma unroll
        for (int p = 0; p < 2; p++) {
            const int idx = p*256 + t;
            const int srow = idx >> 3, su = idx & 7;
            *(short8*)&Ks[swz(srow, su)] =
                *(const short8*)&kb[(baseRow + kt*64 + srow)*DIM + colBase + su*8];
            short8 v8 = *(const short8*)&vb[(baseRow + kt*64 + srow)*DIM + colBase + su*8];
            #pragma unroll
            for (int j = 0; j < 8; j++)
                Vt[swz(su*8 + j, srow >> 3) + (srow & 7)] = (unsigned short)v8[j];
        }
        __syncthreads();

        // K fragments (shared across the wave's m-tiles)
        short8 bk_[4][2];
        #pragma unroll
        for (int nt = 0; nt < 4; nt++)
            #pragma unroll
            for (int kk = 0; kk < 2; kk++)
                bk_[nt][kk] = *(const short8*)&Ks[swz(nt*16 + l15, kk*4 + quad)];
        // V fragments
        short8 bv_[4][2];
        #pragma unroll
        for (int dt = 0; dt < 4; dt++)
            #pragma unroll
            for (int kk = 0; kk < 2; kk++)
                bv_[dt][kk] = *(const short8*)&Vt[swz(dt*16 + l15, kk*4 + quad)];

        #pragma unroll
        for (int m = 0; m < 4; m++) {
            // S = Q K^T  (16 rows x 64 keys)
            f32x4 s_acc[4];
            #pragma unroll
            for (int nt = 0; nt < 4; nt++) s_acc[nt] = (f32x4){0.f,0.f,0.f,0.f};
            #pragma unroll
            for (int kk = 0; kk < 2; kk++)
                #pragma unroll
                for (int nt = 0; nt < 4; nt++)
                    s_acc[nt] = __builtin_amdgcn_mfma_f32_16x16x32_bf16(aq[m][kk], bk_[nt][kk], s_acc[nt], 0, 0, 0);

            // exp (no max subtraction; |s| <~ 3), accumulate row sums, stage P
            #pragma unroll
            for (int nt = 0; nt < 4; nt++) {
                const int ucol = nt*2 + (l15 >> 3);
                const int cofs = l15 & 7;
                #pragma unroll
                for (int r = 0; r < 4; r++) {
                    float e = __expf(s_acc[nt][r] * SCALE);
                    l_part[m][r] += e;
                    Pb[w][swz(quad*4 + r, ucol) + cofs] = f2bf(e);
                }
            }

            // O += P V (read P back as A fragments; same-wave LDS dep)
            short8 ap[2];
            #pragma unroll
            for (int kk = 0; kk < 2; kk++)
                ap[kk] = *(const short8*)&Pb[w][swz(l15, kk*4 + quad)];
            #pragma unroll
            for (int kk = 0; kk < 2; kk++)
                #pragma unroll
                for (int dt = 0; dt < 4; dt++)
                    o_acc[m][dt] = __builtin_amdgcn_mfma_f32_16x16x32_bf16(ap[kk], bv_[dt][kk], o_acc[m][dt], 0, 0, 0);
        }
    }

    // row-sum totals (16-lane reduce per row)
    float l_tot[4][4];
    #pragma unroll
    for (int m = 0; m < 4; m++)
        #pragma unroll
        for (int r = 0; r < 4; r++) {
            float s = l_part[m][r];
            #pragma unroll
            for (int off = 1; off < 16; off <<= 1) s += __shfl_xor(s, off);
            l_tot[m][r] = s;
        }

    // column max over this wave's 64 rows
    #pragma unroll
    for (int dt = 0; dt < 4; dt++) {
        float mx = -1e30f;
        #pragma unroll
        for (int m = 0; m < 4; m++)
            #pragma unroll
            for (int r = 0; r < 4; r++)
                mx = fmaxf(mx, o_acc[m][dt][r] / l_tot[m][r]);
        mx = fmaxf(mx, __shfl_xor(mx, 16));
        mx = fmaxf(mx, __shfl_xor(mx, 32));
        if (quad == 0) cmaxs[w][dt*16 + l15] = mx;
    }
    __syncthreads();
    if (t < 64) {
        float mx = fmaxf(fmaxf(cmaxs[0][t], cmaxs[1][t]), fmaxf(cmaxs[2][t], cmaxs[3][t]));
        a1p[((size_t)whs*2 + yc)*64 + t] = mx;
    }
}

// ---------------------------------------------------------------------------
// K3a: branch-2 partial scores, vectorized short8 loads.
// grid=(60,8), block=256: thread = (pair si*5+tt 0..24, d-oct 0..7).
// ---------------------------------------------------------------------------
__global__ __launch_bounds__(256) void attn2_scores(
    const unsigned short* __restrict__ qb, const unsigned short* __restrict__ kb,
    float* __restrict__ P1)
{
    const int wh = blockIdx.x, ch = blockIdx.y;
    const int wi = wh / HEADS, hi = wh % HEADS;
    const int t = threadIdx.x;
    const int doct = t & 7;
    const int pr = t >> 3;
    if (pr >= 25) return;
    const int si = pr / 5, tt = pr % 5;
    const int colB = hi*HD + doct*8;

    const unsigned short* qrow = qb + ((size_t)(wi*SHOT+si)*LSEQ + ch*64)*DIM + colB;
    const unsigned short* krow = kb + ((size_t)(wi*SHOT+tt)*LSEQ + ch*64)*DIM + colB;

    float acc[8] = {};
    for (int l = 0; l < 64; l++) {
        short8 q8 = *(const short8*)(qrow + (size_t)l*DIM);
        short8 k8 = *(const short8*)(krow + (size_t)l*DIM);
        #pragma unroll
        for (int j = 0; j < 8; j++)
            acc[j] += bf2f((unsigned short)q8[j]) * bf2f((unsigned short)k8[j]);
    }
    #pragma unroll
    for (int j = 0; j < 8; j++)
        P1[((size_t)(wh*25 + pr)*64 + doct*8 + j)*8 + ch] = acc[j];
}

// ---------------------------------------------------------------------------
// K3b: finish softmax + partial weighted-max, vectorized.
// grid=(60,8), block=320.
// ---------------------------------------------------------------------------
__global__ __launch_bounds__(320) void attn2_pmax(
    const float* __restrict__ P1, const unsigned short* __restrict__ vb,
    float* __restrict__ P2)
{
    const int wh = blockIdx.x, ch = blockIdx.y;
    const int wi = wh / HEADS, hi = wh % HEADS;
    const int t = threadIdx.x;
    const int si = t / 64;
    const int r  = t & 63;
    const int doct = r >> 3, lsub = r & 7;

    __shared__ float ssc[SHOT*SHOT*HD];

    for (int e = t; e < SHOT*SHOT*HD; e += 320) {
        const float* p = P1 + (size_t)(wh*25)*64*8 + (size_t)e*8;
        float s = 0.f;
        #pragma unroll
        for (int c = 0; c < 8; c++) s += p[c];
        ssc[e] = s * SCALE;
    }
    __syncthreads();

    float wgt[SHOT][8];
    #pragma unroll
    for (int j = 0; j < 8; j++) {
        const int d = doct*8 + j;
        float sum = 0.f;
        #pragma unroll
        for (int tt = 0; tt < SHOT; tt++) {
            float e = __expf(ssc[(si*SHOT + tt)*HD + d]);
            wgt[tt][j] = e; sum += e;
        }
        const float inv = 1.f / sum;
        #pragma unroll
        for (int tt = 0; tt < SHOT; tt++) wgt[tt][j] *= inv;
    }

    const int colB = hi*HD + doct*8;
    float m[8];
    #pragma unroll
    for (int j = 0; j < 8; j++) m[j] = -1e30f;

    for (int lc = 0; lc < 8; lc++) {
        const int l = ch*64 + lsub*8 + lc;
        float val[8] = {};
        #pragma unroll
        for (int tt = 0; tt < SHOT; tt++) {
            short8 v8 = *(const short8*)(vb + ((size_t)(wi*SHOT+tt)*LSEQ + l)*DIM + colB);
            #pragma unroll
            for (int j = 0; j < 8; j++)
                val[j] += wgt[tt][j] * bf2f((unsigned short)v8[j]);
        }
        #pragma unroll
        for (int j = 0; j < 8; j++) m[j] = fmaxf(m[j], val[j]);
    }

    #pragma unroll
    for (int off = 1; off < 8; off <<= 1)
        #pragma unroll
        for (int j = 0; j < 8; j++) m[j] = fmaxf(m[j], __shfl_xor(m[j], off));

    if (lsub == 0) {
        #pragma unroll
        for (int j = 0; j < 8; j++)
            P2[((size_t)(wh*SHOT + si)*64 + doct*8 + j)*8 + ch] = m[j];
    }
}

// ---------------------------------------------------------------------------
// K4: per-(w,s): partial-max reduces + dual LN + tanh + wp-dot.  grid=25.
// ---------------------------------------------------------------------------
__global__ __launch_bounds__(256) void combine(
    const float* __restrict__ a1p, const float* __restrict__ P2,
    const float* __restrict__ gamma, const float* __restrict__ beta,
    const float* __restrict__ wp, const float* __restrict__ bp,
    float* __restrict__ attn_ws, float* __restrict__ logits)
{
    const int wi = blockIdx.x / SHOT;
    const int si = blockIdx.x % SHOT;
    const int t  = threadIdx.x;

    __shared__ float row1[DIM];
    __shared__ float row2[DIM];
    __shared__ float rbuf[4][4];

    for (int j = t; j < DIM; j += 256) {
        int h = j / HD, d = j % HD;
        const size_t whs = (size_t)(wi*HEADS + h)*SHOT + si;
        row1[j] = fmaxf(a1p[(whs*2 + 0)*64 + d], a1p[(whs*2 + 1)*64 + d]);
        const float* p2 = P2 + (whs*64 + d)*8;
        float mx2 = -1e30f;
        #pragma unroll
        for (int c = 0; c < 8; c++) mx2 = fmaxf(mx2, p2[c]);
        row2[j] = mx2;
    }
    __syncthreads();

    float s1 = 0, q1 = 0, s2 = 0, q2 = 0;
    for (int j = t; j < DIM; j += 256) {
        float x1 = row1[j]; s1 += x1; q1 += x1*x1;
        float x2 = row2[j]; s2 += x2; q2 += x2*x2;
    }
    #pragma unroll
    for (int off = 32; off > 0; off >>= 1) {
        s1 += __shfl_down(s1, off); q1 += __shfl_down(q1, off);
        s2 += __shfl_down(s2, off); q2 += __shfl_down(q2, off);
    }
    const int wid = t / 64, lane = t % 64;
    if (lane == 0) { rbuf[wid][0] = s1; rbuf[wid][1] = q1; rbuf[wid][2] = s2; rbuf[wid][3] = q2; }
    __syncthreads();
    if (t == 0) {
        float a = 0, b = 0, c = 0, dd = 0;
        #pragma unroll
        for (int i = 0; i < 4; i++) { a += rbuf[i][0]; b += rbuf[i][1]; c += rbuf[i][2]; dd += rbuf[i][3]; }
        rbuf[0][0] = a; rbuf[0][1] = b; rbuf[0][2] = c; rbuf[0][3] = dd;
    }
    __syncthreads();
    const float mean1 = rbuf[0][0] / (float)DIM;
    const float var1  = rbuf[0][1] / (float)DIM - mean1*mean1;
    const float mean2 = rbuf[0][2] / (float)DIM;
    const float var2  = rbuf[0][3] / (float)DIM - mean2*mean2;
    const float inv1 = rsqrtf(var1 + 1e-5f);
    const float inv2 = rsqrtf(var2 + 1e-5f);

    float dotp = 0.0f;
    for (int j = t; j < DIM; j += 256) {
        float v1 = (row1[j] - mean1) * inv1 * gamma[j] + beta[j];
        float v2 = (row2[j] - mean2) * inv2 * gamma[j] + beta[j];
        float at = 0.5f * (v1 + v2);
        attn_ws[(size_t)(wi*SHOT + si) * DIM + j] = at;
        dotp += tanhf(at) * wp[j];
    }
    #pragma unroll
    for (int off = 32; off > 0; off >>= 1) dotp += __shfl_down(dotp, off);
    __syncthreads();
    if (lane == 0) rbuf[wid][0] = dotp;
    __syncthreads();
    if (t == 0)
        logits[wi*SHOT + si] = rbuf[0][0] + rbuf[1][0] + rbuf[2][0] + rbuf[3][0] + bp[0];
}

// ---------------------------------------------------------------------------
// K5: shot-softmax + folded output projection.  grid = 60.
// ---------------------------------------------------------------------------
__global__ __launch_bounds__(256) void outproj(
    const float* __restrict__ attn_ws, const float* __restrict__ logits,
    const float* __restrict__ Wo, const float* __restrict__ bo,
    float* __restrict__ out)
{
    const int wi = blockIdx.x / 12;
    const int jg = blockIdx.x % 12;
    const int t  = threadIdx.x;
    __shared__ float P[DIM];

    float lg[SHOT];
    float mx = -1e30f;
    #pragma unroll
    for (int s = 0; s < SHOT; s++) { lg[s] = logits[wi*SHOT + s]; mx = fmaxf(mx, lg[s]); }
    float sum = 0.f;
    #pragma unroll
    for (int s = 0; s < SHOT; s++) { lg[s] = __expf(lg[s] - mx); sum += lg[s]; }
    const float inv = 1.f / sum;

    for (int j = t; j < DIM; j += 256) {
        float a = 0.f;
        #pragma unroll
        for (int s = 0; s < SHOT; s++)
            a += lg[s] * inv * attn_ws[(size_t)(wi*SHOT + s)*DIM + j];
        P[j] = a;
    }
    __syncthreads();

    const int wid = t >> 6, lane = t & 63;
    #pragma unroll
    for (int u = 0; u < 16; u++) {
        const int j = jg*64 + wid*16 + u;
        float acc = 0.f;
        for (int d2 = lane; d2 < DIM; d2 += 64)
            acc += P[d2] * Wo[(size_t)j*DIM + d2];
        #pragma unroll
        for (int off = 32; off > 0; off >>= 1) acc += __shfl_down(acc, off);
        if (lane == 0) out[(size_t)wi*DIM + j] = acc + 5.0f*bo[j];
    }
}

// ---------------------------------------------------------------------------
extern "C" void kernel_launch(void* const* d_in, const int* in_sizes, int n_in,
                              void* d_out, int out_size, void* d_ws, size_t ws_size,
                              hipStream_t stream) {
    const float* X     = (const float*)d_in[0];
    const float* Wq    = (const float*)d_in[1];
    const float* bq    = (const float*)d_in[2];
    const float* Wk    = (const float*)d_in[3];
    const float* bk    = (const float*)d_in[4];
    const float* Wv    = (const float*)d_in[5];
    const float* bv    = (const float*)d_in[6];
    const float* gamma = (const float*)d_in[7];
    const float* beta  = (const float*)d_in[8];
    const float* wp    = (const float*)d_in[9];
    const float* bp    = (const float*)d_in[10];
    const float* Wo    = (const float*)d_in[11];
    const float* bo    = (const float*)d_in[12];
    float* out = (float*)d_out;

    unsigned short* Xb   = (unsigned short*)d_ws;
    unsigned short* Wb   = Xb + NXEL;
    unsigned short* qkvb = Wb + 3*NWEL;
    unsigned short* qb = qkvb;
    unsigned short* kb = qkvb + NXEL;
    unsigned short* vb = qkvb + 2*NXEL;

    float* a1p    = (float*)(qkvb + 3*NXEL);
    float* P1     = a1p + (size_t)WAY*HEADS*SHOT*2*64;
    float* P2     = P1 + (size_t)WAY*HEADS*SHOT*SHOT*64*8;
    float* attn_b = P2 + (size_t)WAY*HEADS*SHOT*64*8;
    float* logits = attn_b + (size_t)WAY*SHOT*DIM;

    const int castN = NX4 + 3*NW4;
    cast_all<<<(castN + 255)/256, 256, 0, stream>>>(X, Wq, Wk, Wv, Xb, Wb);

    dim3 g1(DIM/128, NROWS/128, 3);
    qkv_mfma<<<g1, 256, 0, stream>>>(Xb, Wb, bq, bk, bv, qkvb);

    dim3 g2(WAY*HEADS*SHOT, 2);
    attn1_mfma<<<g2, 256, 0, stream>>>(qb, kb, vb, a1p);

    dim3 g3(WAY*HEADS, 8);
    attn2_scores<<<g3, 256, 0, stream>>>(qb, kb, P1);
    attn2_pmax<<<g3, 320, 0, stream>>>(P1, vb, P2);

    combine<<<WAY*SHOT, 256, 0, stream>>>(a1p, P2, gamma, beta, wp, bp, attn_b, logits);
    outproj<<<WAY*12, 256, 0, stream>>>(attn_b, logits, Wo, bo, out);
}

// Round 6
// 361.246 us; speedup vs baseline: 1.0779x; 1.0779x over previous
//
#include <hip/hip_runtime.h>
#include <math.h>

#define WAY 5
#define SHOT 5
#define HEADS 12
#define DIM 768
#define LSEQ 512
#define HD 64
#define NROWS (WAY*SHOT*LSEQ)   // 12800
#define SCALE 0.125f
#define NXEL ((size_t)NROWS*DIM)
#define NWEL ((size_t)DIM*DIM)
#define CH2 16                  // attn2 l-chunks (32 l each)

typedef __attribute__((ext_vector_type(8))) short short8;
typedef __attribute__((ext_vector_type(4))) float f32x4;
typedef __attribute__((ext_vector_type(4))) unsigned short ushort4v;

__device__ __forceinline__ float bf2f(unsigned short u) {
    union { unsigned int i; float f; } x; x.i = ((unsigned int)u) << 16; return x.f;
}
__device__ __forceinline__ unsigned short f2bf(float f) {
    union { float f; unsigned int i; } x; x.f = f;
    unsigned int r = x.i + 0x7FFFu + ((x.i >> 16) & 1u);
    return (unsigned short)(r >> 16);
}

// ---------------------------------------------------------------------------
// K0: all fp32->bf16 casts in one launch.
// ---------------------------------------------------------------------------
#define NX4 (NROWS*DIM/4)
#define NW4 (DIM*DIM/4)
__global__ __launch_bounds__(256) void cast_all(
    const float* __restrict__ X, const float* __restrict__ Wq,
    const float* __restrict__ Wk, const float* __restrict__ Wv,
    unsigned short* __restrict__ Xb, unsigned short* __restrict__ Wb)
{
    int i = blockIdx.x * 256 + threadIdx.x;
    const float* s; unsigned short* d; int off;
    if (i < NX4)               { s = X;  d = Xb;            off = i; }
    else if (i < NX4 + NW4)    { s = Wq; d = Wb;            off = i - NX4; }
    else if (i < NX4 + 2*NW4)  { s = Wk; d = Wb + NWEL;     off = i - NX4 - NW4; }
    else if (i < NX4 + 3*NW4)  { s = Wv; d = Wb + 2*NWEL;   off = i - NX4 - 2*NW4; }
    else return;
    float4 f = ((const float4*)s)[off];
    ushort4v o;
    o.x = f2bf(f.x); o.y = f2bf(f.y); o.z = f2bf(f.z); o.w = f2bf(f.w);
    *(ushort4v*)(d + (size_t)off*4) = o;
}

// ---------------------------------------------------------------------------
// K1: fused QKV projection, bf16 MFMA 16x16x32, 128x128 tile, BK=32
// (16 KB LDS -> best occupancy), global_load_lds width-16.
// grid = (6, 100, 3), block = 256.
// ---------------------------------------------------------------------------
__global__ __launch_bounds__(256) void qkv_mfma(
    const unsigned short* __restrict__ Xb, const unsigned short* __restrict__ Wball,
    const float* __restrict__ bq, const float* __restrict__ bk, const float* __restrict__ bv,
    unsigned short* __restrict__ qkv_out)
{
    const int which = blockIdx.z;
    const unsigned short* W = Wball + (size_t)which * NWEL;
    const float* bias = (which == 0) ? bq : ((which == 1) ? bk : bv);
    unsigned short* out = qkv_out + (size_t)which * NXEL;

    const int m0 = blockIdx.y * 128;
    const int n0 = blockIdx.x * 128;

    __shared__ __align__(16) unsigned short Ab[128*32];
    __shared__ __align__(16) unsigned short Bb[128*32];

    const int t = threadIdx.x;
    const int w = t >> 6;
    const int lane = t & 63;
    const int quad = lane >> 4;
    const int l15 = lane & 15;
    const int wm = (w & 1) * 64;
    const int wn = (w >> 1) * 64;

    f32x4 acc[4][4];
    #pragma unroll
    for (int i = 0; i < 4; i++)
        #pragma unroll
        for (int j = 0; j < 4; j++)
            acc[i][j] = (f32x4){0.f, 0.f, 0.f, 0.f};

    const int srow = lane >> 2;
    const int schunk = (lane & 3) * 8;

    for (int k0 = 0; k0 < DIM; k0 += 32) {
        #pragma unroll
        for (int c = 0; c < 2; c++) {
            const unsigned short* gA = Xb + (size_t)(m0 + w*32 + c*16 + srow)*DIM + k0 + schunk;
            const unsigned short* gB = W  + (size_t)(n0 + w*32 + c*16 + srow)*DIM + k0 + schunk;
            __builtin_amdgcn_global_load_lds(
                (const __attribute__((address_space(1))) unsigned int*)gA,
                (__attribute__((address_space(3))) unsigned int*)&Ab[(w*32 + c*16)*32], 16, 0, 0);
            __builtin_amdgcn_global_load_lds(
                (const __attribute__((address_space(1))) unsigned int*)gB,
                (__attribute__((address_space(3))) unsigned int*)&Bb[(w*32 + c*16)*32], 16, 0, 0);
        }
        __syncthreads();

        short8 af[4], bf_[4];
        #pragma unroll
        for (int i = 0; i < 4; i++) af[i]  = *(const short8*)&Ab[(wm + i*16 + l15)*32 + quad*8];
        #pragma unroll
        for (int j = 0; j < 4; j++) bf_[j] = *(const short8*)&Bb[(wn + j*16 + l15)*32 + quad*8];
        #pragma unroll
        for (int i = 0; i < 4; i++)
            #pragma unroll
            for (int j = 0; j < 4; j++)
                acc[i][j] = __builtin_amdgcn_mfma_f32_16x16x32_bf16(af[i], bf_[j], acc[i][j], 0, 0, 0);
        __syncthreads();
    }

    #pragma unroll
    for (int j = 0; j < 4; j++) {
        const int col = n0 + wn + j*16 + l15;
        const float bv_ = bias[col];
        #pragma unroll
        for (int i = 0; i < 4; i++) {
            #pragma unroll
            for (int r = 0; r < 4; r++) {
                const int row = m0 + wm + i*16 + quad*4 + r;
                out[(size_t)row*DIM + col] = f2bf(acc[i][j][r] + bv_);
            }
        }
    }
}

// XOR-swizzled LDS addressing: 64-ushort (128 B) rows, 8 x 16B units per row.
__device__ __forceinline__ int swz(int row, int u) {
    return row*64 + ((u ^ (row & 7)) << 3);
}

// ---------------------------------------------------------------------------
// K2: branch-1 token attention (R3 structure: low VGPR, high occupancy).
// grid = (300 whs, 8 chunks), block = 256 (4 waves x 16 q-rows).
// Unnormalized exp (scores tiny), per-lane row-sum partials, one end
// reduction.  a1p[(whs*8+chunk)*64 + d] = per-chunk column max.
// ---------------------------------------------------------------------------
__global__ __launch_bounds__(256) void attn1_mfma(
    const unsigned short* __restrict__ qb, const unsigned short* __restrict__ kb,
    const unsigned short* __restrict__ vb, float* __restrict__ a1p)
{
    int whs = blockIdx.x;
    const int chunk = blockIdx.y;
    const int si = whs % SHOT;  whs /= SHOT;
    const int hi = whs % HEADS; whs /= HEADS;
    const int wi = whs;
    const size_t baseRow = (size_t)(wi*SHOT + si) * LSEQ;
    const int colBase = hi * HD;

    __shared__ __align__(16) unsigned short Qs[64*64];
    __shared__ __align__(16) unsigned short Ks[64*64];
    __shared__ __align__(16) unsigned short Vt[64*64];
    __shared__ __align__(16) unsigned short Pb[64*64];
    __shared__ float cmaxs[4][64];

    const int t = threadIdx.x;
    const int w = t >> 6;
    const int lane = t & 63;
    const int quad = lane >> 4;
    const int l15 = lane & 15;

    #pragma unroll
    for (int p = 0; p < 2; p++) {
        int idx = p*256 + t;
        int row = idx >> 3, u = idx & 7;
        *(short8*)&Qs[swz(row, u)] =
            *(const short8*)&qb[(baseRow + chunk*64 + row)*DIM + colBase + u*8];
    }

    float l_part[4] = {0.f, 0.f, 0.f, 0.f};
    f32x4 o_acc[4];
    #pragma unroll
    for (int d = 0; d < 4; d++) o_acc[d] = (f32x4){0.f, 0.f, 0.f, 0.f};

    for (int kt = 0; kt < 8; kt++) {
        __syncthreads();
        #pragma unroll
        for (int p = 0; p < 2; p++) {
            int idx = p*256 + t;
            int row = idx >> 3, u = idx & 7;
            *(short8*)&Ks[swz(row, u)] =
                *(const short8*)&kb[(baseRow + kt*64 + row)*DIM + colBase + u*8];
        }
        #pragma unroll
        for (int p = 0; p < 2; p++) {
            int idx = p*256 + t;
            int d = idx & 63, lc = idx >> 6;
            unsigned short tmp[8];
            #pragma unroll
            for (int jj = 0; jj < 8; jj++)
                tmp[jj] = vb[(baseRow + kt*64 + lc*8 + jj)*DIM + colBase + d];
            *(short8*)&Vt[swz(d, lc)] = *(const short8*)tmp;
        }
        __syncthreads();

        // S = Q K^T
        f32x4 s_acc[4];
        #pragma unroll
        for (int nt = 0; nt < 4; nt++) s_acc[nt] = (f32x4){0.f, 0.f, 0.f, 0.f};
        short8 aq[2];
        #pragma unroll
        for (int kk = 0; kk < 2; kk++)
            aq[kk] = *(const short8*)&Qs[swz(w*16 + l15, kk*4 + quad)];
        #pragma unroll
        for (int kk = 0; kk < 2; kk++) {
            #pragma unroll
            for (int nt = 0; nt < 4; nt++) {
                short8 bk_ = *(const short8*)&Ks[swz(nt*16 + l15, kk*4 + quad)];
                s_acc[nt] = __builtin_amdgcn_mfma_f32_16x16x32_bf16(aq[kk], bk_, s_acc[nt], 0, 0, 0);
            }
        }

        // e = exp(s*SCALE), no max-subtraction; accumulate per-lane row sums
        #pragma unroll
        for (int nt = 0; nt < 4; nt++) {
            #pragma unroll
            for (int r = 0; r < 4; r++) {
                float e = __expf(s_acc[nt][r] * SCALE);
                s_acc[nt][r] = e;
                l_part[r] += e;
            }
        }

        // write P (bf16) into wave-private Pb rows
        #pragma unroll
        for (int nt = 0; nt < 4; nt++) {
            int ucol = nt*2 + (l15 >> 3);
            int cofs = l15 & 7;
            #pragma unroll
            for (int r = 0; r < 4; r++) {
                int row = w*16 + quad*4 + r;
                Pb[swz(row, ucol) + cofs] = f2bf(s_acc[nt][r]);
            }
        }

        // O += P V
        short8 ap[2];
        #pragma unroll
        for (int kk = 0; kk < 2; kk++)
            ap[kk] = *(const short8*)&Pb[swz(w*16 + l15, kk*4 + quad)];
        #pragma unroll
        for (int kk = 0; kk < 2; kk++) {
            #pragma unroll
            for (int dt = 0; dt < 4; dt++) {
                short8 bv_ = *(const short8*)&Vt[swz(dt*16 + l15, kk*4 + quad)];
                o_acc[dt] = __builtin_amdgcn_mfma_f32_16x16x32_bf16(ap[kk], bv_, o_acc[dt], 0, 0, 0);
            }
        }
    }

    float l_tot[4];
    #pragma unroll
    for (int r = 0; r < 4; r++) {
        float s = l_part[r];
        #pragma unroll
        for (int off = 1; off < 16; off <<= 1) s += __shfl_xor(s, off);
        l_tot[r] = s;
    }

    float cm[4];
    #pragma unroll
    for (int dt = 0; dt < 4; dt++) {
        float mx = -1e30f;
        #pragma unroll
        for (int r = 0; r < 4; r++) mx = fmaxf(mx, o_acc[dt][r] / l_tot[r]);
        mx = fmaxf(mx, __shfl_xor(mx, 16));
        mx = fmaxf(mx, __shfl_xor(mx, 32));
        cm[dt] = mx;
    }
    if (quad == 0) {
        #pragma unroll
        for (int dt = 0; dt < 4; dt++) cmaxs[w][dt*16 + l15] = cm[dt];
    }
    __syncthreads();
    if (t < 64) {
        float mx = fmaxf(fmaxf(cmaxs[0][t], cmaxs[1][t]), fmaxf(cmaxs[2][t], cmaxs[3][t]));
        a1p[((size_t)blockIdx.x*8 + chunk)*64 + t] = mx;
    }
}

// ---------------------------------------------------------------------------
// K3a: branch-2 partial scores over 32-l chunks.  grid=(60,CH2), block=256:
// thread = (pair si*5+tt 0..24, d-oct 0..7).
// ---------------------------------------------------------------------------
__global__ __launch_bounds__(256) void attn2_scores(
    const unsigned short* __restrict__ qb, const unsigned short* __restrict__ kb,
    float* __restrict__ P1)
{
    const int wh = blockIdx.x, ch = blockIdx.y;
    const int wi = wh / HEADS, hi = wh % HEADS;
    const int t = threadIdx.x;
    const int doct = t & 7;
    const int pr = t >> 3;
    if (pr >= 25) return;
    const int si = pr / 5, tt = pr % 5;
    const int colB = hi*HD + doct*8;

    const unsigned short* qrow = qb + ((size_t)(wi*SHOT+si)*LSEQ + ch*32)*DIM + colB;
    const unsigned short* krow = kb + ((size_t)(wi*SHOT+tt)*LSEQ + ch*32)*DIM + colB;

    float acc[8] = {};
    for (int l = 0; l < 32; l++) {
        short8 q8 = *(const short8*)(qrow + (size_t)l*DIM);
        short8 k8 = *(const short8*)(krow + (size_t)l*DIM);
        #pragma unroll
        for (int j = 0; j < 8; j++)
            acc[j] += bf2f((unsigned short)q8[j]) * bf2f((unsigned short)k8[j]);
    }
    #pragma unroll
    for (int j = 0; j < 8; j++)
        P1[((size_t)(wh*25 + pr)*64 + doct*8 + j)*CH2 + ch] = acc[j];
}

// ---------------------------------------------------------------------------
// K3b: reduce chunk partials + softmax over tt -> normalized weights.
// grid=60, block=512.
// ---------------------------------------------------------------------------
__global__ __launch_bounds__(512) void attn2_sm(
    const float* __restrict__ P1, float* __restrict__ wgt)
{
    const int wh = blockIdx.x;
    const int t = threadIdx.x;
    __shared__ float ssc[SHOT*SHOT*HD];

    for (int e = t; e < SHOT*SHOT*HD; e += 512) {
        const float* p = P1 + ((size_t)(wh*25)*64 + e)*CH2;
        float s = 0.f;
        #pragma unroll
        for (int c = 0; c < CH2; c++) s += p[c];
        ssc[e] = s * SCALE;
    }
    __syncthreads();

    if (t < SHOT*HD) {
        const int si = t >> 6, d = t & 63;
        float e5[SHOT];
        float sum = 0.f;
        #pragma unroll
        for (int tt = 0; tt < SHOT; tt++) {
            float e = __expf(ssc[(si*SHOT + tt)*HD + d]);
            e5[tt] = e; sum += e;
        }
        const float inv = 1.f / sum;
        #pragma unroll
        for (int tt = 0; tt < SHOT; tt++)
            wgt[((size_t)(wh*25) + si*5 + tt)*64 + d] = e5[tt] * inv;
    }
}

// ---------------------------------------------------------------------------
// K3c: weighted-max over own 32-l chunk using precomputed weights.
// grid=(60,CH2), block=320: thread = (si wave, d-oct, l-sub).
// ---------------------------------------------------------------------------
__global__ __launch_bounds__(320) void attn2_pmax(
    const float* __restrict__ wgt, const unsigned short* __restrict__ vb,
    float* __restrict__ P2)
{
    const int wh = blockIdx.x, ch = blockIdx.y;
    const int wi = wh / HEADS, hi = wh % HEADS;
    const int t = threadIdx.x;
    const int si = t / 64;
    const int r  = t & 63;
    const int doct = r >> 3, lsub = r & 7;

    float wloc[SHOT][8];
    #pragma unroll
    for (int tt = 0; tt < SHOT; tt++) {
        float4 a = *(const float4*)&wgt[((size_t)(wh*25) + si*5 + tt)*64 + doct*8];
        float4 b = *(const float4*)&wgt[((size_t)(wh*25) + si*5 + tt)*64 + doct*8 + 4];
        wloc[tt][0]=a.x; wloc[tt][1]=a.y; wloc[tt][2]=a.z; wloc[tt][3]=a.w;
        wloc[tt][4]=b.x; wloc[tt][5]=b.y; wloc[tt][6]=b.z; wloc[tt][7]=b.w;
    }

    const int colB = hi*HD + doct*8;
    float m[8];
    #pragma unroll
    for (int j = 0; j < 8; j++) m[j] = -1e30f;

    for (int lc = 0; lc < 4; lc++) {
        const int l = ch*32 + lsub*4 + lc;
        float val[8] = {};
        #pragma unroll
        for (int tt = 0; tt < SHOT; tt++) {
            short8 v8 = *(const short8*)(vb + ((size_t)(wi*SHOT+tt)*LSEQ + l)*DIM + colB);
            #pragma unroll
            for (int j = 0; j < 8; j++)
                val[j] += wloc[tt][j] * bf2f((unsigned short)v8[j]);
        }
        #pragma unroll
        for (int j = 0; j < 8; j++) m[j] = fmaxf(m[j], val[j]);
    }

    #pragma unroll
    for (int off = 1; off < 8; off <<= 1)
        #pragma unroll
        for (int j = 0; j < 8; j++) m[j] = fmaxf(m[j], __shfl_xor(m[j], off));

    if (lsub == 0) {
        #pragma unroll
        for (int j = 0; j < 8; j++)
            P2[((size_t)(wh*SHOT + si)*64 + doct*8 + j)*CH2 + ch] = m[j];
    }
}

// ---------------------------------------------------------------------------
// K4: per-(w,s): chunk-max reduces + dual LN + tanh + wp-dot.  grid=25.
// ---------------------------------------------------------------------------
__global__ __launch_bounds__(256) void combine(
    const float* __restrict__ a1p, const float* __restrict__ P2,
    const float* __restrict__ gamma, const float* __restrict__ beta,
    const float* __restrict__ wp, const float* __restrict__ bp,
    float* __restrict__ attn_ws, float* __restrict__ logits)
{
    const int wi = blockIdx.x / SHOT;
    const int si = blockIdx.x % SHOT;
    const int t  = threadIdx.x;

    __shared__ float row1[DIM];
    __shared__ float row2[DIM];
    __shared__ float rbuf[4][4];

    for (int j = t; j < DIM; j += 256) {
        int h = j / HD, d = j % HD;
        const size_t whs = (size_t)(wi*HEADS + h)*SHOT + si;
        const float* p1 = a1p + (whs*8)*64 + d;
        float mx = -1e30f;
        #pragma unroll
        for (int c = 0; c < 8; c++) mx = fmaxf(mx, p1[c * 64]);
        row1[j] = mx;
        const float* p2 = P2 + (whs*64 + d)*CH2;
        float mx2 = -1e30f;
        #pragma unroll
        for (int c = 0; c < CH2; c++) mx2 = fmaxf(mx2, p2[c]);
        row2[j] = mx2;
    }
    __syncthreads();

    float s1 = 0, q1 = 0, s2 = 0, q2 = 0;
    for (int j = t; j < DIM; j += 256) {
        float x1 = row1[j]; s1 += x1; q1 += x1*x1;
        float x2 = row2[j]; s2 += x2; q2 += x2*x2;
    }
    #pragma unroll
    for (int off = 32; off > 0; off >>= 1) {
        s1 += __shfl_down(s1, off); q1 += __shfl_down(q1, off);
        s2 += __shfl_down(s2, off); q2 += __shfl_down(q2, off);
    }
    const int wid = t / 64, lane = t % 64;
    if (lane == 0) { rbuf[wid][0] = s1; rbuf[wid][1] = q1; rbuf[wid][2] = s2; rbuf[wid][3] = q2; }
    __syncthreads();
    if (t == 0) {
        float a = 0, b = 0, c = 0, dd = 0;
        #pragma unroll
        for (int i = 0; i < 4; i++) { a += rbuf[i][0]; b += rbuf[i][1]; c += rbuf[i][2]; dd += rbuf[i][3]; }
        rbuf[0][0] = a; rbuf[0][1] = b; rbuf[0][2] = c; rbuf[0][3] = dd;
    }
    __syncthreads();
    const float mean1 = rbuf[0][0] / (float)DIM;
    const float var1  = rbuf[0][1] / (float)DIM - mean1*mean1;
    const float mean2 = rbuf[0][2] / (float)DIM;
    const float var2  = rbuf[0][3] / (float)DIM - mean2*mean2;
    const float inv1 = rsqrtf(var1 + 1e-5f);
    const float inv2 = rsqrtf(var2 + 1e-5f);

    float dotp = 0.0f;
    for (int j = t; j < DIM; j += 256) {
        float v1 = (row1[j] - mean1) * inv1 * gamma[j] + beta[j];
        float v2 = (row2[j] - mean2) * inv2 * gamma[j] + beta[j];
        float at = 0.5f * (v1 + v2);
        attn_ws[(size_t)(wi*SHOT + si) * DIM + j] = at;
        dotp += tanhf(at) * wp[j];
    }
    #pragma unroll
    for (int off = 32; off > 0; off >>= 1) dotp += __shfl_down(dotp, off);
    __syncthreads();
    if (lane == 0) rbuf[wid][0] = dotp;
    __syncthreads();
    if (t == 0)
        logits[wi*SHOT + si] = rbuf[0][0] + rbuf[1][0] + rbuf[2][0] + rbuf[3][0] + bp[0];
}

// ---------------------------------------------------------------------------
// K5: shot-softmax + folded output projection.  grid = 60.
// ---------------------------------------------------------------------------
__global__ __launch_bounds__(256) void outproj(
    const float* __restrict__ attn_ws, const float* __restrict__ logits,
    const float* __restrict__ Wo, const float* __restrict__ bo,
    float* __restrict__ out)
{
    const int wi = blockIdx.x / 12;
    const int jg = blockIdx.x % 12;
    const int t  = threadIdx.x;
    __shared__ float P[DIM];

    float lg[SHOT];
    float mx = -1e30f;
    #pragma unroll
    for (int s = 0; s < SHOT; s++) { lg[s] = logits[wi*SHOT + s]; mx = fmaxf(mx, lg[s]); }
    float sum = 0.f;
    #pragma unroll
    for (int s = 0; s < SHOT; s++) { lg[s] = __expf(lg[s] - mx); sum += lg[s]; }
    const float inv = 1.f / sum;

    for (int j = t; j < DIM; j += 256) {
        float a = 0.f;
        #pragma unroll
        for (int s = 0; s < SHOT; s++)
            a += lg[s] * inv * attn_ws[(size_t)(wi*SHOT + s)*DIM + j];
        P[j] = a;
    }
    __syncthreads();

    const int wid = t >> 6, lane = t & 63;
    #pragma unroll
    for (int u = 0; u < 16; u++) {
        const int j = jg*64 + wid*16 + u;
        float acc = 0.f;
        for (int d2 = lane; d2 < DIM; d2 += 64)
            acc += P[d2] * Wo[(size_t)j*DIM + d2];
        #pragma unroll
        for (int off = 32; off > 0; off >>= 1) acc += __shfl_down(acc, off);
        if (lane == 0) out[(size_t)wi*DIM + j] = acc + 5.0f*bo[j];
    }
}

// ---------------------------------------------------------------------------
extern "C" void kernel_launch(void* const* d_in, const int* in_sizes, int n_in,
                              void* d_out, int out_size, void* d_ws, size_t ws_size,
                              hipStream_t stream) {
    const float* X     = (const float*)d_in[0];
    const float* Wq    = (const float*)d_in[1];
    const float* bq    = (const float*)d_in[2];
    const float* Wk    = (const float*)d_in[3];
    const float* bk    = (const float*)d_in[4];
    const float* Wv    = (const float*)d_in[5];
    const float* bv    = (const float*)d_in[6];
    const float* gamma = (const float*)d_in[7];
    const float* beta  = (const float*)d_in[8];
    const float* wp    = (const float*)d_in[9];
    const float* bp    = (const float*)d_in[10];
    const float* Wo    = (const float*)d_in[11];
    const float* bo    = (const float*)d_in[12];
    float* out = (float*)d_out;

    unsigned short* Xb   = (unsigned short*)d_ws;
    unsigned short* Wb   = Xb + NXEL;
    unsigned short* qkvb = Wb + 3*NWEL;
    unsigned short* qb = qkvb;
    unsigned short* kb = qkvb + NXEL;
    unsigned short* vb = qkvb + 2*NXEL;

    float* a1p    = (float*)(qkvb + 3*NXEL);
    float* P1     = a1p + (size_t)WAY*HEADS*SHOT*8*64;            // 153,600
    float* wgt    = P1 + (size_t)WAY*HEADS*25*64*CH2;             // 1,536,000
    float* P2     = wgt + (size_t)WAY*HEADS*25*64;                // 96,000
    float* attn_b = P2 + (size_t)WAY*HEADS*SHOT*64*CH2;           // 307,200
    float* logits = attn_b + (size_t)WAY*SHOT*DIM;                // 19,200

    const int castN = NX4 + 3*NW4;
    cast_all<<<(castN + 255)/256, 256, 0, stream>>>(X, Wq, Wk, Wv, Xb, Wb);

    dim3 g1(DIM/128, NROWS/128, 3);
    qkv_mfma<<<g1, 256, 0, stream>>>(Xb, Wb, bq, bk, bv, qkvb);

    dim3 g2(WAY*HEADS*SHOT, 8);
    attn1_mfma<<<g2, 256, 0, stream>>>(qb, kb, vb, a1p);

    dim3 g3(WAY*HEADS, CH2);
    attn2_scores<<<g3, 256, 0, stream>>>(qb, kb, P1);
    attn2_sm<<<WAY*HEADS, 512, 0, stream>>>(P1, wgt);
    attn2_pmax<<<g3, 320, 0, stream>>>(wgt, vb, P2);

    combine<<<WAY*SHOT, 256, 0, stream>>>(a1p, P2, gamma, beta, wp, bp, attn_b, logits);
    outproj<<<WAY*12, 256, 0, stream>>>(attn_b, logits, Wo, bo, out);
}